// Round 6
// baseline (128.293 us; speedup 1.0000x reference)
//
#include <hip/hip_runtime.h>

#define NB 4
#define LQ 512
#define LK 512
#define EE 128
#define DD 256

__device__ __forceinline__ float fast_rcp(float x) { return __builtin_amdgcn_rcpf(x); }

// K1: rows 0..2047 = query@Wc1 -> EqT[b][e][q] = exp(2q) TRANSPOSED;
//     rows 2048..4095 = key@Wc2 -> Ek[b][l][e] = exp(2k) row-major.
// 4 rows/block (1024 blocks, 4/CU -> 16 waves/CU), 256 thr = 2 row-pairs x 128 cols.
// d-loop unrolled x8 -> 8 independent W loads in flight per iteration.
__global__ __launch_bounds__(256) void proj_exp_kernel(
    const float* __restrict__ query, const float* __restrict__ key,
    const float* __restrict__ Wc1, const float* __restrict__ Wc2,
    float* __restrict__ EqT, float* __restrict__ Ek)
{
    __shared__ float in_s[4][DD];   // 4 KB
    const int r0 = blockIdx.x * 4;
    const bool is_q = (r0 < NB * LQ);
    const float* src = is_q ? query : key;
    const float* W   = is_q ? Wc1   : Wc2;
    const int rbase  = is_q ? r0    : r0 - NB * LQ;

    // stage 4 rows = 1024 floats = 256 float4 (one per thread, coalesced)
    ((float4*)in_s)[threadIdx.x] = ((const float4*)(src + (size_t)rbase * DD))[threadIdx.x];
    __syncthreads();

    const int c  = threadIdx.x & 127;
    const int rg = threadIdx.x >> 7;   // 0..1 -> rows rg*2, rg*2+1 (wave-uniform)
    float acc0 = 0.f, acc1 = 0.f;
    for (int d = 0; d < DD; d += 8) {
        float w0 = W[(d + 0) * EE + c];
        float w1 = W[(d + 1) * EE + c];
        float w2 = W[(d + 2) * EE + c];
        float w3 = W[(d + 3) * EE + c];
        float w4 = W[(d + 4) * EE + c];
        float w5 = W[(d + 5) * EE + c];
        float w6 = W[(d + 6) * EE + c];
        float w7 = W[(d + 7) * EE + c];
        const float4 xa0 = *(const float4*)&in_s[rg * 2 + 0][d];
        const float4 xb0 = *(const float4*)&in_s[rg * 2 + 0][d + 4];
        const float4 xa1 = *(const float4*)&in_s[rg * 2 + 1][d];
        const float4 xb1 = *(const float4*)&in_s[rg * 2 + 1][d + 4];
        acc0 += xa0.x * w0 + xa0.y * w1 + xa0.z * w2 + xa0.w * w3
              + xb0.x * w4 + xb0.y * w5 + xb0.z * w6 + xb0.w * w7;
        acc1 += xa1.x * w0 + xa1.y * w1 + xa1.z * w2 + xa1.w * w3
              + xb1.x * w4 + xb1.y * w5 + xb1.z * w6 + xb1.w * w7;
    }
    if (is_q) {
        // rows are consecutive q for column e=c -> float2 store
        const int b    = rbase >> 9;
        const int qloc = (rbase & 511) + rg * 2;
        float2 o;
        o.x = __expf(2.0f * acc0);
        o.y = __expf(2.0f * acc1);
        *(float2*)&EqT[((size_t)(b * EE + c)) * LQ + qloc] = o;
    } else {
        Ek[(size_t)(rbase + rg * 2 + 0) * EE + c] = __expf(2.0f * acc0);
        Ek[(size_t)(rbase + rg * 2 + 1) * EE + c] = __expf(2.0f * acc1);
    }
}

// K2: block = (b, 4 l-rows), 512 threads, thread owns q = tid.
// tanh(x) = 1 - 2/(e^{2x}+1): sjt = vcsum - 2*sum_e vc_e/(EqT*Ek+1).
// Ek tile (4x128) + vc staged in LDS once -> main loop has only 4 coalesced
// EqT loads + LDS broadcasts per iteration (no per-iter global/scalar deps).
__global__ __launch_bounds__(512) void atten_kernel(
    const float* __restrict__ EqT, const float* __restrict__ Ek,
    const float* __restrict__ vc, float* __restrict__ attn)
{
    __shared__ float  sj_s[4][LQ];      // 8 KB
    __shared__ float  ek_s[4][EE];      // 2 KB
    __shared__ float  vc_s[EE];         // 0.5 KB
    __shared__ float2 mZ_s[4][2];
    __shared__ float  scale_s[4][2];
    const int b   = blockIdx.x >> 7;
    const int lt  = blockIdx.x & 127;
    const int l0  = lt * 4;
    const int tid = threadIdx.x;
    const int q   = tid;
    const float* eqc = EqT + (size_t)b * EE * LQ + q;          // column base; stride LQ per e
    const float* ekb = Ek  + ((size_t)b * LK + l0) * EE;       // 4 contiguous rows

    ((float*)ek_s)[tid] = ekb[tid];                            // 512 floats, coalesced
    if (tid < EE) vc_s[tid] = vc[tid];
    __syncthreads();

    float vcsum = 0.f;
    #pragma unroll
    for (int e = 0; e < EE; e += 4) {
        const float4 v = *(const float4*)&vc_s[e];
        vcsum += (v.x + v.y) + (v.z + v.w);
    }

    float s2[4] = {0.f, 0.f, 0.f, 0.f};
    for (int e = 0; e < EE; e += 4) {
        const float a0 = eqc[(size_t)(e + 0) * LQ];            // coalesced
        const float a1 = eqc[(size_t)(e + 1) * LQ];
        const float a2 = eqc[(size_t)(e + 2) * LQ];
        const float a3 = eqc[(size_t)(e + 3) * LQ];
        const float4 vv = *(const float4*)&vc_s[e];            // LDS broadcast
        #pragma unroll
        for (int l = 0; l < 4; ++l) {
            const float4 kk = *(const float4*)&ek_s[l][e];     // LDS broadcast
            s2[l] += vv.x * fast_rcp(a0 * kk.x + 1.0f);
            s2[l] += vv.y * fast_rcp(a1 * kk.y + 1.0f);
            s2[l] += vv.z * fast_rcp(a2 * kk.z + 1.0f);
            s2[l] += vv.w * fast_rcp(a3 * kk.w + 1.0f);
        }
    }
    #pragma unroll
    for (int l = 0; l < 4; ++l)
        sj_s[l][q] = vcsum - 2.0f * s2[l];
    __syncthreads();

    // softmax over q: wave w handles (l = w&3, q-half h2 = w>>2)
    const int w = tid >> 6, lane = tid & 63;
    const int l = w & 3, h2 = w >> 2, base = h2 * 256;
    float m = -1e30f;
    #pragma unroll
    for (int i = 0; i < 4; ++i) m = fmaxf(m, sj_s[l][base + lane + 64 * i]);
    #pragma unroll
    for (int off = 32; off >= 1; off >>= 1) m = fmaxf(m, __shfl_xor(m, off));
    float Z = 0.f;
    #pragma unroll
    for (int i = 0; i < 4; ++i) {
        const int idx = base + lane + 64 * i;
        const float ex = __expf(sj_s[l][idx] - m);
        sj_s[l][idx] = ex;                                    // lane-exclusive
        Z += ex;
    }
    #pragma unroll
    for (int off = 32; off >= 1; off >>= 1) Z += __shfl_xor(Z, off);
    if (lane == 0) mZ_s[l][h2] = make_float2(m, Z);
    __syncthreads();
    if (lane == 0) {
        const float2 A = mZ_s[l][0], B2 = mZ_s[l][1];
        const float M  = fmaxf(A.x, B2.x);
        const float Zt = A.y * __expf(A.x - M) + B2.y * __expf(B2.x - M);
        scale_s[l][h2] = __expf((h2 ? B2.x : A.x) - M) * fast_rcp(Zt);
    }
    __syncthreads();

    #pragma unroll
    for (int li = 0; li < 4; ++li)
        attn[(size_t)(b * LK + l0 + li) * LQ + q] = sj_s[li][q] * scale_s[li][q >> 8];
}

// K3: context[b,l,:] = sum_q atten[b,l,q] * value[b,q,:]
// block = (b, 4 l-rows), 512 blocks x 512 threads = 8 q-groups(g) x 64 d-lanes.
// 2 blocks/CU, 16 waves/CU (4/SIMD) -- double R5's TLP. Per iter: 8 independent
// loads (4 attn broadcast + 4 value coalesced float4), 64 FMA.
// 3-stage LDS tree reduce (16 KB). Overwrites EqT/Ek region (safe: K2 done).
__global__ __launch_bounds__(512) void context_kernel(
    const float* __restrict__ attn, const float* __restrict__ value,
    float* __restrict__ ctx)
{
    const int b    = blockIdx.x >> 7;
    const int lt   = blockIdx.x & 127;
    const int row0 = b * LK + lt * 4;
    const int tid  = threadIdx.x;
    const int g    = tid >> 6;      // q-group 0..7 -> q in [g*64, g*64+64)
    const int lane = tid & 63;      // d float4 chunk
    const float4* v4 = (const float4*)(value + (size_t)b * LQ * DD);

    float4 ac[4];
    #pragma unroll
    for (int l = 0; l < 4; ++l) ac[l] = make_float4(0.f, 0.f, 0.f, 0.f);

    const int q0 = g * 64;
    for (int q = q0; q < q0 + 64; q += 4) {
        float4 a[4];
        #pragma unroll
        for (int l = 0; l < 4; ++l)
            a[l] = *(const float4*)(attn + (size_t)(row0 + l) * LQ + q);  // broadcast
        const float4 v0 = v4[(size_t)(q + 0) * 64 + lane];                // coalesced
        const float4 v1 = v4[(size_t)(q + 1) * 64 + lane];
        const float4 v2 = v4[(size_t)(q + 2) * 64 + lane];
        const float4 v3 = v4[(size_t)(q + 3) * 64 + lane];
        #pragma unroll
        for (int l = 0; l < 4; ++l) {
            ac[l].x += a[l].x * v0.x; ac[l].y += a[l].x * v0.y;
            ac[l].z += a[l].x * v0.z; ac[l].w += a[l].x * v0.w;
            ac[l].x += a[l].y * v1.x; ac[l].y += a[l].y * v1.y;
            ac[l].z += a[l].y * v1.z; ac[l].w += a[l].y * v1.w;
            ac[l].x += a[l].z * v2.x; ac[l].y += a[l].z * v2.y;
            ac[l].z += a[l].z * v2.z; ac[l].w += a[l].z * v2.w;
            ac[l].x += a[l].w * v3.x; ac[l].y += a[l].w * v3.y;
            ac[l].z += a[l].w * v3.z; ac[l].w += a[l].w * v3.w;
        }
    }

    // tree reduce over the 8 q-groups: 8 -> 4 -> 2 -> 1
    __shared__ float4 red[4][4][64];   // 16 KB
    if (g >= 4) {
        #pragma unroll
        for (int l = 0; l < 4; ++l) red[g - 4][l][lane] = ac[l];
    }
    __syncthreads();
    if (g < 4) {
        #pragma unroll
        for (int l = 0; l < 4; ++l) {
            const float4 r = red[g][l][lane];
            ac[l].x += r.x; ac[l].y += r.y; ac[l].z += r.z; ac[l].w += r.w;
        }
    }
    __syncthreads();
    if (g == 2 || g == 3) {
        #pragma unroll
        for (int l = 0; l < 4; ++l) red[g - 2][l][lane] = ac[l];
    }
    __syncthreads();
    if (g < 2) {
        #pragma unroll
        for (int l = 0; l < 4; ++l) {
            const float4 r = red[g][l][lane];
            ac[l].x += r.x; ac[l].y += r.y; ac[l].z += r.z; ac[l].w += r.w;
        }
    }
    __syncthreads();
    if (g == 1) {
        #pragma unroll
        for (int l = 0; l < 4; ++l) red[0][l][lane] = ac[l];
    }
    __syncthreads();
    if (g == 0) {
        #pragma unroll
        for (int l = 0; l < 4; ++l) {
            const float4 r = red[0][l][lane];
            ac[l].x += r.x; ac[l].y += r.y; ac[l].z += r.z; ac[l].w += r.w;
            ((float4*)ctx)[(size_t)(row0 + l) * 64 + lane] = ac[l];
        }
    }
}

extern "C" void kernel_launch(void* const* d_in, const int* in_sizes, int n_in,
                              void* d_out, int out_size, void* d_ws, size_t ws_size,
                              hipStream_t stream) {
    const float* query = (const float*)d_in[0];
    const float* key   = (const float*)d_in[1];
    const float* value = (const float*)d_in[2];
    const float* Wc1   = (const float*)d_in[3];
    const float* Wc2   = (const float*)d_in[4];
    const float* vc    = (const float*)d_in[5];

    float* ctx  = (float*)d_out;                          // [B, Lk, D]   = 524288 floats
    float* attn = (float*)d_out + (size_t)NB * LK * DD;   // [B, Lk, Lq]  = 1048576 floats

    // Scratch lives inside d_out's ctx region (exactly 2*NB*LQ*EE = 524288 floats).
    // K1 writes EqT/Ek there; K2 reads them and writes attn (disjoint);
    // K3 then overwrites the ctx region with the final context.
    // NOTE: do NOT use d_ws -- R1 empirically showed its re-poison races the
    // timed stream (first call passed, all later calls corrupted).
    float* EqT = ctx;                                     // [B, E, Lq] = 262144 floats
    float* Ek  = ctx + (size_t)NB * LQ * EE;              // [B, Lk, E] = 262144 floats

    proj_exp_kernel<<<dim3(1024), dim3(256), 0, stream>>>(query, key, Wc1, Wc2, EqT, Ek);
    atten_kernel<<<dim3(NB * (LK / 4)), dim3(512), 0, stream>>>(EqT, Ek, vc, attn);
    context_kernel<<<dim3(NB * (LK / 4)), dim3(512), 0, stream>>>(attn, value, ctx);
}

// Round 7
// 121.340 us; speedup vs baseline: 1.0573x; 1.0573x over previous
//
#include <hip/hip_runtime.h>

#define NB 4
#define LQ 512
#define LK 512
#define EE 128
#define DD 256

__device__ __forceinline__ float fast_rcp(float x) { return __builtin_amdgcn_rcpf(x); }

// K1: rows 0..2047 = query@Wc1 -> EqT[b][e][q] = exp(2q) TRANSPOSED;
//     rows 2048..4095 = key@Wc2 -> Ek[b][l][e] = exp(2k) row-major.
// 8 rows/block (512 blocks), 256 thr = 2 row-groups x 128 cols, 4 rows/thread.
// d-loop unrolled x8 -> 8 independent W loads in flight per iteration.
__global__ __launch_bounds__(256) void proj_exp_kernel(
    const float* __restrict__ query, const float* __restrict__ key,
    const float* __restrict__ Wc1, const float* __restrict__ Wc2,
    float* __restrict__ EqT, float* __restrict__ Ek)
{
    __shared__ float in_s[8][DD];   // 8 KB
    const int r0 = blockIdx.x * 8;
    const bool is_q = (r0 < NB * LQ);
    const float* src = is_q ? query : key;
    const float* W   = is_q ? Wc1   : Wc2;
    const int rbase  = is_q ? r0    : r0 - NB * LQ;

    const float4* srow4 = (const float4*)(src + (size_t)rbase * DD);
    #pragma unroll
    for (int i = 0; i < 2; ++i)
        ((float4*)in_s)[i * 256 + threadIdx.x] = srow4[i * 256 + threadIdx.x];
    __syncthreads();

    const int c  = threadIdx.x & 127;
    const int rg = threadIdx.x >> 7;   // 0..1 -> rows rg*4 .. rg*4+3 (wave-uniform)
    float acc[4] = {0.f, 0.f, 0.f, 0.f};
    for (int d = 0; d < DD; d += 8) {
        const float w0 = W[(d + 0) * EE + c];
        const float w1 = W[(d + 1) * EE + c];
        const float w2 = W[(d + 2) * EE + c];
        const float w3 = W[(d + 3) * EE + c];
        const float w4 = W[(d + 4) * EE + c];
        const float w5 = W[(d + 5) * EE + c];
        const float w6 = W[(d + 6) * EE + c];
        const float w7 = W[(d + 7) * EE + c];
        #pragma unroll
        for (int i = 0; i < 4; ++i) {
            const float4 xa = *(const float4*)&in_s[rg * 4 + i][d];      // broadcast
            const float4 xb = *(const float4*)&in_s[rg * 4 + i][d + 4];
            acc[i] += xa.x * w0 + xa.y * w1 + xa.z * w2 + xa.w * w3
                    + xb.x * w4 + xb.y * w5 + xb.z * w6 + xb.w * w7;
        }
    }
    if (is_q) {
        // thread holds 4 consecutive q for column e=c -> float4 store
        const int b    = rbase >> 9;
        const int qloc = (rbase & 511) + rg * 4;
        float4 o;
        o.x = __expf(2.0f * acc[0]); o.y = __expf(2.0f * acc[1]);
        o.z = __expf(2.0f * acc[2]); o.w = __expf(2.0f * acc[3]);
        *(float4*)&EqT[((size_t)(b * EE + c)) * LQ + qloc] = o;
    } else {
        #pragma unroll
        for (int i = 0; i < 4; ++i)
            Ek[(size_t)(rbase + rg * 4 + i) * EE + c] = __expf(2.0f * acc[i]);
    }
}

// K2: block = (b, 4 l-rows), 512 threads.
// Thread mapping: qq = tid&127 owns q = 4*qq..4*qq+3 (float4 EqT loads, coalesced),
// eg = tid>>7 owns e in [eg*32, eg*32+32). Per iteration: ONE float4 load feeds
// 16 rcp + 32 fma (load:work 1:48). Cross-eg reduce via one LDS stage.
// tanh(x) = 1 - 2/(e^{2x}+1): sjt = vcsum - 2*sum_e vc_e/(EqT*Ek+1).
__global__ __launch_bounds__(512) void atten_kernel(
    const float* __restrict__ EqT, const float* __restrict__ Ek,
    const float* __restrict__ vc, float* __restrict__ attn)
{
    __shared__ float  ek_s[4][EE];      // 2 KB
    __shared__ float  vc_s[EE];         // 0.5 KB
    __shared__ float  s2p_s[3][4][LQ];  // 24 KB (partials from eg=1..3)
    __shared__ float  sj_s[4][LQ];      // 8 KB
    __shared__ float2 mZ_s[4][2];
    __shared__ float  scale_s[4][2];
    const int b   = blockIdx.x >> 7;
    const int lt  = blockIdx.x & 127;
    const int l0  = lt * 4;
    const int tid = threadIdx.x;
    const int qq  = tid & 127;          // q-quad
    const int eg  = tid >> 7;           // e-group

    // stage Ek tile (4 rows) + vc
    ((float*)ek_s)[tid] = Ek[((size_t)b * LK + l0) * EE + tid];   // 512 floats, coalesced
    if (tid < EE) vc_s[tid] = vc[tid];
    __syncthreads();

    float vcsum = 0.f;
    #pragma unroll
    for (int e = 0; e < EE; e += 4) {
        const float4 v = *(const float4*)&vc_s[e];   // broadcast
        vcsum += (v.x + v.y) + (v.z + v.w);
    }

    const float4* eq4 = (const float4*)(EqT + (size_t)b * EE * LQ);
    float s2[4][4];
    #pragma unroll
    for (int l = 0; l < 4; ++l) { s2[l][0]=0.f; s2[l][1]=0.f; s2[l][2]=0.f; s2[l][3]=0.f; }

    #pragma unroll 4
    for (int i = 0; i < 32; ++i) {
        const int e = eg * 32 + i;
        const float4 a  = eq4[(size_t)e * 128 + qq];   // coalesced float4
        const float  vv = vc_s[e];                     // broadcast
        #pragma unroll
        for (int l = 0; l < 4; ++l) {
            const float kk = ek_s[l][e];               // broadcast
            s2[l][0] += vv * fast_rcp(a.x * kk + 1.0f);
            s2[l][1] += vv * fast_rcp(a.y * kk + 1.0f);
            s2[l][2] += vv * fast_rcp(a.z * kk + 1.0f);
            s2[l][3] += vv * fast_rcp(a.w * kk + 1.0f);
        }
    }

    // reduce over the 4 e-groups
    if (eg > 0) {
        #pragma unroll
        for (int l = 0; l < 4; ++l)
            *(float4*)&s2p_s[eg - 1][l][qq * 4] =
                make_float4(s2[l][0], s2[l][1], s2[l][2], s2[l][3]);
    }
    __syncthreads();
    if (eg == 0) {
        #pragma unroll
        for (int l = 0; l < 4; ++l) {
            const float4 p0 = *(const float4*)&s2p_s[0][l][qq * 4];
            const float4 p1 = *(const float4*)&s2p_s[1][l][qq * 4];
            const float4 p2 = *(const float4*)&s2p_s[2][l][qq * 4];
            float4 sj;
            sj.x = vcsum - 2.0f * (s2[l][0] + p0.x + p1.x + p2.x);
            sj.y = vcsum - 2.0f * (s2[l][1] + p0.y + p1.y + p2.y);
            sj.z = vcsum - 2.0f * (s2[l][2] + p0.z + p1.z + p2.z);
            sj.w = vcsum - 2.0f * (s2[l][3] + p0.w + p1.w + p2.w);
            *(float4*)&sj_s[l][qq * 4] = sj;
        }
    }
    __syncthreads();

    // softmax over q: wave w handles (l = w&3, q-half h2 = w>>2)
    const int w = tid >> 6, lane = tid & 63;
    const int l = w & 3, h2 = w >> 2, base = h2 * 256;
    float m = -1e30f;
    #pragma unroll
    for (int i = 0; i < 4; ++i) m = fmaxf(m, sj_s[l][base + lane + 64 * i]);
    #pragma unroll
    for (int off = 32; off >= 1; off >>= 1) m = fmaxf(m, __shfl_xor(m, off));
    float Z = 0.f;
    #pragma unroll
    for (int i = 0; i < 4; ++i) {
        const int idx = base + lane + 64 * i;
        const float ex = __expf(sj_s[l][idx] - m);
        sj_s[l][idx] = ex;                                    // lane-exclusive
        Z += ex;
    }
    #pragma unroll
    for (int off = 32; off >= 1; off >>= 1) Z += __shfl_xor(Z, off);
    if (lane == 0) mZ_s[l][h2] = make_float2(m, Z);
    __syncthreads();
    if (lane == 0) {
        const float2 A = mZ_s[l][0], B2 = mZ_s[l][1];
        const float M  = fmaxf(A.x, B2.x);
        const float Zt = A.y * __expf(A.x - M) + B2.y * __expf(B2.x - M);
        scale_s[l][h2] = __expf((h2 ? B2.x : A.x) - M) * fast_rcp(Zt);
    }
    __syncthreads();

    const int q = tid;
    #pragma unroll
    for (int li = 0; li < 4; ++li)
        attn[(size_t)(b * LK + l0 + li) * LQ + q] = sj_s[li][q] * scale_s[li][q >> 8];
}

// K3: context[b,l,:] = sum_q atten[b,l,q] * value[b,q,:]
// block = (b, 4 l-rows), 512 blocks x 512 threads = 8 q-groups(g) x 64 d-lanes.
// 2 blocks/CU, 16 waves/CU (4/SIMD). Per iter: 8 independent loads
// (4 attn broadcast + 4 value coalesced float4), 64 FMA.
// 3-stage LDS tree reduce (16 KB). Overwrites EqT/Ek region (safe: K2 done).
__global__ __launch_bounds__(512) void context_kernel(
    const float* __restrict__ attn, const float* __restrict__ value,
    float* __restrict__ ctx)
{
    const int b    = blockIdx.x >> 7;
    const int lt   = blockIdx.x & 127;
    const int row0 = b * LK + lt * 4;
    const int tid  = threadIdx.x;
    const int g    = tid >> 6;      // q-group 0..7 -> q in [g*64, g*64+64)
    const int lane = tid & 63;      // d float4 chunk
    const float4* v4 = (const float4*)(value + (size_t)b * LQ * DD);

    float4 ac[4];
    #pragma unroll
    for (int l = 0; l < 4; ++l) ac[l] = make_float4(0.f, 0.f, 0.f, 0.f);

    const int q0 = g * 64;
    for (int q = q0; q < q0 + 64; q += 4) {
        float4 a[4];
        #pragma unroll
        for (int l = 0; l < 4; ++l)
            a[l] = *(const float4*)(attn + (size_t)(row0 + l) * LQ + q);  // broadcast
        const float4 v0 = v4[(size_t)(q + 0) * 64 + lane];                // coalesced
        const float4 v1 = v4[(size_t)(q + 1) * 64 + lane];
        const float4 v2 = v4[(size_t)(q + 2) * 64 + lane];
        const float4 v3 = v4[(size_t)(q + 3) * 64 + lane];
        #pragma unroll
        for (int l = 0; l < 4; ++l) {
            ac[l].x += a[l].x * v0.x; ac[l].y += a[l].x * v0.y;
            ac[l].z += a[l].x * v0.z; ac[l].w += a[l].x * v0.w;
            ac[l].x += a[l].y * v1.x; ac[l].y += a[l].y * v1.y;
            ac[l].z += a[l].y * v1.z; ac[l].w += a[l].y * v1.w;
            ac[l].x += a[l].z * v2.x; ac[l].y += a[l].z * v2.y;
            ac[l].z += a[l].z * v2.z; ac[l].w += a[l].z * v2.w;
            ac[l].x += a[l].w * v3.x; ac[l].y += a[l].w * v3.y;
            ac[l].z += a[l].w * v3.z; ac[l].w += a[l].w * v3.w;
        }
    }

    // tree reduce over the 8 q-groups: 8 -> 4 -> 2 -> 1
    __shared__ float4 red[4][4][64];   // 16 KB
    if (g >= 4) {
        #pragma unroll
        for (int l = 0; l < 4; ++l) red[g - 4][l][lane] = ac[l];
    }
    __syncthreads();
    if (g < 4) {
        #pragma unroll
        for (int l = 0; l < 4; ++l) {
            const float4 r = red[g][l][lane];
            ac[l].x += r.x; ac[l].y += r.y; ac[l].z += r.z; ac[l].w += r.w;
        }
    }
    __syncthreads();
    if (g == 2 || g == 3) {
        #pragma unroll
        for (int l = 0; l < 4; ++l) red[g - 2][l][lane] = ac[l];
    }
    __syncthreads();
    if (g < 2) {
        #pragma unroll
        for (int l = 0; l < 4; ++l) {
            const float4 r = red[g][l][lane];
            ac[l].x += r.x; ac[l].y += r.y; ac[l].z += r.z; ac[l].w += r.w;
        }
    }
    __syncthreads();
    if (g == 1) {
        #pragma unroll
        for (int l = 0; l < 4; ++l) red[0][l][lane] = ac[l];
    }
    __syncthreads();
    if (g == 0) {
        #pragma unroll
        for (int l = 0; l < 4; ++l) {
            const float4 r = red[0][l][lane];
            ac[l].x += r.x; ac[l].y += r.y; ac[l].z += r.z; ac[l].w += r.w;
            ((float4*)ctx)[(size_t)(row0 + l) * 64 + lane] = ac[l];
        }
    }
}

extern "C" void kernel_launch(void* const* d_in, const int* in_sizes, int n_in,
                              void* d_out, int out_size, void* d_ws, size_t ws_size,
                              hipStream_t stream) {
    const float* query = (const float*)d_in[0];
    const float* key   = (const float*)d_in[1];
    const float* value = (const float*)d_in[2];
    const float* Wc1   = (const float*)d_in[3];
    const float* Wc2   = (const float*)d_in[4];
    const float* vc    = (const float*)d_in[5];

    float* ctx  = (float*)d_out;                          // [B, Lk, D]   = 524288 floats
    float* attn = (float*)d_out + (size_t)NB * LK * DD;   // [B, Lk, Lq]  = 1048576 floats

    // Scratch lives inside d_out's ctx region (exactly 2*NB*LQ*EE = 524288 floats).
    // K1 writes EqT/Ek there; K2 reads them and writes attn (disjoint);
    // K3 then overwrites the ctx region with the final context.
    // NOTE: do NOT use d_ws -- R1 empirically showed its re-poison races the
    // timed stream (first call passed, all later calls corrupted).
    float* EqT = ctx;                                     // [B, E, Lq] = 262144 floats
    float* Ek  = ctx + (size_t)NB * LQ * EE;              // [B, Lk, E] = 262144 floats

    proj_exp_kernel<<<dim3(512), dim3(256), 0, stream>>>(query, key, Wc1, Wc2, EqT, Ek);
    atten_kernel<<<dim3(NB * (LK / 4)), dim3(512), 0, stream>>>(EqT, Ek, vc, attn);
    context_kernel<<<dim3(NB * (LK / 4)), dim3(512), 0, stream>>>(attn, value, ctx);
}

// Round 8
// 119.700 us; speedup vs baseline: 1.0718x; 1.0137x over previous
//
#include <hip/hip_runtime.h>

#define NB 4
#define LQ 512
#define LK 512
#define EE 128
#define DD 256

__device__ __forceinline__ float fast_rcp(float x) { return __builtin_amdgcn_rcpf(x); }

// K1: rows 0..2047 = query@Wc1 -> EqT[b][e][q] = exp(2q) TRANSPOSED;
//     rows 2048..4095 = key@Wc2 -> Ek[b][l][e] = exp(2k) row-major.
// 8 rows/block (512 blocks), 256 thr = 2 row-groups x 128 cols, 4 rows/thread.
__global__ __launch_bounds__(256) void proj_exp_kernel(
    const float* __restrict__ query, const float* __restrict__ key,
    const float* __restrict__ Wc1, const float* __restrict__ Wc2,
    float* __restrict__ EqT, float* __restrict__ Ek)
{
    __shared__ float in_s[8][DD];   // 8 KB
    const int r0 = blockIdx.x * 8;
    const bool is_q = (r0 < NB * LQ);
    const float* src = is_q ? query : key;
    const float* W   = is_q ? Wc1   : Wc2;
    const int rbase  = is_q ? r0    : r0 - NB * LQ;

    const float4* srow4 = (const float4*)(src + (size_t)rbase * DD);
    #pragma unroll
    for (int i = 0; i < 2; ++i)
        ((float4*)in_s)[i * 256 + threadIdx.x] = srow4[i * 256 + threadIdx.x];
    __syncthreads();

    const int c  = threadIdx.x & 127;
    const int rg = threadIdx.x >> 7;   // 0..1 -> rows rg*4 .. rg*4+3 (wave-uniform)
    float acc[4] = {0.f, 0.f, 0.f, 0.f};
    for (int d = 0; d < DD; d += 8) {
        const float w0 = W[(d + 0) * EE + c];
        const float w1 = W[(d + 1) * EE + c];
        const float w2 = W[(d + 2) * EE + c];
        const float w3 = W[(d + 3) * EE + c];
        const float w4 = W[(d + 4) * EE + c];
        const float w5 = W[(d + 5) * EE + c];
        const float w6 = W[(d + 6) * EE + c];
        const float w7 = W[(d + 7) * EE + c];
        #pragma unroll
        for (int i = 0; i < 4; ++i) {
            const float4 xa = *(const float4*)&in_s[rg * 4 + i][d];      // broadcast
            const float4 xb = *(const float4*)&in_s[rg * 4 + i][d + 4];
            acc[i] += xa.x * w0 + xa.y * w1 + xa.z * w2 + xa.w * w3
                    + xb.x * w4 + xb.y * w5 + xb.z * w6 + xb.w * w7;
        }
    }
    if (is_q) {
        // thread holds 4 consecutive q for column e=c -> float4 store
        const int b    = rbase >> 9;
        const int qloc = (rbase & 511) + rg * 4;
        float4 o;
        o.x = __expf(2.0f * acc[0]); o.y = __expf(2.0f * acc[1]);
        o.z = __expf(2.0f * acc[2]); o.w = __expf(2.0f * acc[3]);
        *(float4*)&EqT[((size_t)(b * EE + c)) * LQ + qloc] = o;
    } else {
        #pragma unroll
        for (int i = 0; i < 4; ++i)
            Ek[(size_t)(rbase + rg * 4 + i) * EE + c] = __expf(2.0f * acc[i]);
    }
}

// K2: block = (b, 4 l-rows), 512 threads.
// qq = tid&127 owns q = 4*qq..4*qq+3 (coalesced float4 EqT loads),
// eg = tid>>7 owns e in [eg*32, eg*32+32). One float4 load feeds 16 rcp + 32 fma.
// tanh(x) = 1 - 2/(e^{2x}+1): sjt = vcsum - 2*sum_e vc_e/(EqT*Ek+1).
__global__ __launch_bounds__(512) void atten_kernel(
    const float* __restrict__ EqT, const float* __restrict__ Ek,
    const float* __restrict__ vc, float* __restrict__ attn)
{
    __shared__ float  ek_s[4][EE];      // 2 KB
    __shared__ float  vc_s[EE];         // 0.5 KB
    __shared__ float  s2p_s[3][4][LQ];  // 24 KB (partials from eg=1..3)
    __shared__ float  sj_s[4][LQ];      // 8 KB
    __shared__ float2 mZ_s[4][2];
    __shared__ float  scale_s[4][2];
    const int b   = blockIdx.x >> 7;
    const int lt  = blockIdx.x & 127;
    const int l0  = lt * 4;
    const int tid = threadIdx.x;
    const int qq  = tid & 127;          // q-quad
    const int eg  = tid >> 7;           // e-group

    ((float*)ek_s)[tid] = Ek[((size_t)b * LK + l0) * EE + tid];   // 512 floats, coalesced
    if (tid < EE) vc_s[tid] = vc[tid];
    __syncthreads();

    float vcsum = 0.f;
    #pragma unroll
    for (int e = 0; e < EE; e += 4) {
        const float4 v = *(const float4*)&vc_s[e];   // broadcast
        vcsum += (v.x + v.y) + (v.z + v.w);
    }

    const float4* eq4 = (const float4*)(EqT + (size_t)b * EE * LQ);
    float s2[4][4];
    #pragma unroll
    for (int l = 0; l < 4; ++l) { s2[l][0]=0.f; s2[l][1]=0.f; s2[l][2]=0.f; s2[l][3]=0.f; }

    #pragma unroll 4
    for (int i = 0; i < 32; ++i) {
        const int e = eg * 32 + i;
        const float4 a  = eq4[(size_t)e * 128 + qq];   // coalesced float4
        const float  vv = vc_s[e];                     // broadcast
        #pragma unroll
        for (int l = 0; l < 4; ++l) {
            const float kk = ek_s[l][e];               // broadcast
            s2[l][0] += vv * fast_rcp(a.x * kk + 1.0f);
            s2[l][1] += vv * fast_rcp(a.y * kk + 1.0f);
            s2[l][2] += vv * fast_rcp(a.z * kk + 1.0f);
            s2[l][3] += vv * fast_rcp(a.w * kk + 1.0f);
        }
    }

    // reduce over the 4 e-groups
    if (eg > 0) {
        #pragma unroll
        for (int l = 0; l < 4; ++l)
            *(float4*)&s2p_s[eg - 1][l][qq * 4] =
                make_float4(s2[l][0], s2[l][1], s2[l][2], s2[l][3]);
    }
    __syncthreads();
    if (eg == 0) {
        #pragma unroll
        for (int l = 0; l < 4; ++l) {
            const float4 p0 = *(const float4*)&s2p_s[0][l][qq * 4];
            const float4 p1 = *(const float4*)&s2p_s[1][l][qq * 4];
            const float4 p2 = *(const float4*)&s2p_s[2][l][qq * 4];
            float4 sj;
            sj.x = vcsum - 2.0f * (s2[l][0] + p0.x + p1.x + p2.x);
            sj.y = vcsum - 2.0f * (s2[l][1] + p0.y + p1.y + p2.y);
            sj.z = vcsum - 2.0f * (s2[l][2] + p0.z + p1.z + p2.z);
            sj.w = vcsum - 2.0f * (s2[l][3] + p0.w + p1.w + p2.w);
            *(float4*)&sj_s[l][qq * 4] = sj;
        }
    }
    __syncthreads();

    // softmax over q: wave w handles (l = w&3, q-half h2 = w>>2)
    const int w = tid >> 6, lane = tid & 63;
    const int l = w & 3, h2 = w >> 2, base = h2 * 256;
    float m = -1e30f;
    #pragma unroll
    for (int i = 0; i < 4; ++i) m = fmaxf(m, sj_s[l][base + lane + 64 * i]);
    #pragma unroll
    for (int off = 32; off >= 1; off >>= 1) m = fmaxf(m, __shfl_xor(m, off));
    float Z = 0.f;
    #pragma unroll
    for (int i = 0; i < 4; ++i) {
        const int idx = base + lane + 64 * i;
        const float ex = __expf(sj_s[l][idx] - m);
        sj_s[l][idx] = ex;                                    // lane-exclusive
        Z += ex;
    }
    #pragma unroll
    for (int off = 32; off >= 1; off >>= 1) Z += __shfl_xor(Z, off);
    if (lane == 0) mZ_s[l][h2] = make_float2(m, Z);
    __syncthreads();
    if (lane == 0) {
        const float2 A = mZ_s[l][0], B2 = mZ_s[l][1];
        const float M  = fmaxf(A.x, B2.x);
        const float Zt = A.y * __expf(A.x - M) + B2.y * __expf(B2.x - M);
        scale_s[l][h2] = __expf((h2 ? B2.x : A.x) - M) * fast_rcp(Zt);
    }
    __syncthreads();

    const int q = tid;
    #pragma unroll
    for (int li = 0; li < 4; ++li)
        attn[(size_t)(b * LK + l0 + li) * LQ + q] = sj_s[li][q] * scale_s[li][q >> 8];
}

// K3: context[b,l,:] = sum_q atten[b,l,q] * value[b,q,:]
// block = (b, 8 l-rows): 256 blocks x 1024 threads = 16 q-groups(g) x 64 d-lanes.
// 1 block/CU but 16 waves/CU; each block reads value[b] exactly once (128 MB L2
// total). Per iter: 4 indep coalesced value float4 + 8 uniform attn float4 ->
// 128 FMA. 4-stage LDS tree reduce (64 KB). Overwrites EqT/Ek region (K2 done).
__global__ __launch_bounds__(1024) void context_kernel(
    const float* __restrict__ attn, const float* __restrict__ value,
    float* __restrict__ ctx)
{
    const int b    = blockIdx.x >> 6;
    const int lt   = blockIdx.x & 63;
    const int row0 = b * LK + lt * 8;
    const int tid  = threadIdx.x;
    const int g    = tid >> 6;      // q-group 0..15 -> q in [g*32, g*32+32)
    const int lane = tid & 63;      // d float4 chunk
    const float4* v4 = (const float4*)(value + (size_t)b * LQ * DD);

    float4 ac[8];
    #pragma unroll
    for (int l = 0; l < 8; ++l) ac[l] = make_float4(0.f, 0.f, 0.f, 0.f);

    const int q0 = g * 32;
    for (int q = q0; q < q0 + 32; q += 4) {
        float4 a[8];
        #pragma unroll
        for (int l = 0; l < 8; ++l)
            a[l] = *(const float4*)(attn + (size_t)(row0 + l) * LQ + q);  // uniform -> broadcast
        const float4 v0 = v4[(size_t)(q + 0) * 64 + lane];                // coalesced
        const float4 v1 = v4[(size_t)(q + 1) * 64 + lane];
        const float4 v2 = v4[(size_t)(q + 2) * 64 + lane];
        const float4 v3 = v4[(size_t)(q + 3) * 64 + lane];
        #pragma unroll
        for (int l = 0; l < 8; ++l) {
            ac[l].x += a[l].x * v0.x; ac[l].y += a[l].x * v0.y;
            ac[l].z += a[l].x * v0.z; ac[l].w += a[l].x * v0.w;
            ac[l].x += a[l].y * v1.x; ac[l].y += a[l].y * v1.y;
            ac[l].z += a[l].y * v1.z; ac[l].w += a[l].y * v1.w;
            ac[l].x += a[l].z * v2.x; ac[l].y += a[l].z * v2.y;
            ac[l].z += a[l].z * v2.z; ac[l].w += a[l].z * v2.w;
            ac[l].x += a[l].w * v3.x; ac[l].y += a[l].w * v3.y;
            ac[l].z += a[l].w * v3.z; ac[l].w += a[l].w * v3.w;
        }
    }

    // tree reduce over the 16 q-groups: 16 -> 8 -> 4 -> 2 -> 1
    __shared__ float4 red[8][8][64];   // 64 KB
    if (g >= 8) {
        #pragma unroll
        for (int l = 0; l < 8; ++l) red[g - 8][l][lane] = ac[l];
    }
    __syncthreads();
    if (g < 8) {
        #pragma unroll
        for (int l = 0; l < 8; ++l) {
            const float4 r = red[g][l][lane];
            ac[l].x += r.x; ac[l].y += r.y; ac[l].z += r.z; ac[l].w += r.w;
        }
    }
    __syncthreads();
    if (g >= 4 && g < 8) {
        #pragma unroll
        for (int l = 0; l < 8; ++l) red[g - 4][l][lane] = ac[l];
    }
    __syncthreads();
    if (g < 4) {
        #pragma unroll
        for (int l = 0; l < 8; ++l) {
            const float4 r = red[g][l][lane];
            ac[l].x += r.x; ac[l].y += r.y; ac[l].z += r.z; ac[l].w += r.w;
        }
    }
    __syncthreads();
    if (g == 2 || g == 3) {
        #pragma unroll
        for (int l = 0; l < 8; ++l) red[g - 2][l][lane] = ac[l];
    }
    __syncthreads();
    if (g < 2) {
        #pragma unroll
        for (int l = 0; l < 8; ++l) {
            const float4 r = red[g][l][lane];
            ac[l].x += r.x; ac[l].y += r.y; ac[l].z += r.z; ac[l].w += r.w;
        }
    }
    __syncthreads();
    if (g == 1) {
        #pragma unroll
        for (int l = 0; l < 8; ++l) red[0][l][lane] = ac[l];
    }
    __syncthreads();
    if (g == 0) {
        #pragma unroll
        for (int l = 0; l < 8; ++l) {
            const float4 r = red[0][l][lane];
            ac[l].x += r.x; ac[l].y += r.y; ac[l].z += r.z; ac[l].w += r.w;
            ((float4*)ctx)[(size_t)(row0 + l) * 64 + lane] = ac[l];
        }
    }
}

extern "C" void kernel_launch(void* const* d_in, const int* in_sizes, int n_in,
                              void* d_out, int out_size, void* d_ws, size_t ws_size,
                              hipStream_t stream) {
    const float* query = (const float*)d_in[0];
    const float* key   = (const float*)d_in[1];
    const float* value = (const float*)d_in[2];
    const float* Wc1   = (const float*)d_in[3];
    const float* Wc2   = (const float*)d_in[4];
    const float* vc    = (const float*)d_in[5];

    float* ctx  = (float*)d_out;                          // [B, Lk, D]   = 524288 floats
    float* attn = (float*)d_out + (size_t)NB * LK * DD;   // [B, Lk, Lq]  = 1048576 floats

    // Scratch lives inside d_out's ctx region (exactly 2*NB*LQ*EE = 524288 floats).
    // K1 writes EqT/Ek there; K2 reads them and writes attn (disjoint);
    // K3 then overwrites the ctx region with the final context.
    // NOTE: do NOT use d_ws -- R1 empirically showed its re-poison races the
    // timed stream (first call passed, all later calls corrupted).
    float* EqT = ctx;                                     // [B, E, Lq] = 262144 floats
    float* Ek  = ctx + (size_t)NB * LQ * EE;              // [B, Lk, E] = 262144 floats

    proj_exp_kernel<<<dim3(512), dim3(256), 0, stream>>>(query, key, Wc1, Wc2, EqT, Ek);
    atten_kernel<<<dim3(NB * (LK / 4)), dim3(512), 0, stream>>>(EqT, Ek, vc, attn);
    context_kernel<<<dim3(NB * (LK / 8)), dim3(1024), 0, stream>>>(attn, value, ctx);
}